// Round 1
// 740.976 us; speedup vs baseline: 1.0568x; 1.0568x over previous
//
#include <hip/hip_runtime.h>

typedef __bf16 bf16x8 __attribute__((ext_vector_type(8)));
typedef __bf16 bf16x4 __attribute__((ext_vector_type(4)));
typedef float f32x4 __attribute__((ext_vector_type(4)));

#define SCALE 0.17677669529663687f  // 1/sqrt(32)

// ---------- weight cast+transpose, 5 weights fused in one launch ----------
__global__ __launch_bounds__(256) void castw_kernel(
    const float* __restrict__ W0, const float* __restrict__ W1,
    const float* __restrict__ W2, const float* __restrict__ W3,
    const float* __restrict__ W4,
    __bf16* __restrict__ T0, __bf16* __restrict__ T1,
    __bf16* __restrict__ T2, __bf16* __restrict__ T3,
    __bf16* __restrict__ T4) {
  int which = blockIdx.x >> 8;
  const float* W = which == 0 ? W0 : which == 1 ? W1 : which == 2 ? W2 : which == 3 ? W3 : W4;
  __bf16* T = which == 0 ? T0 : which == 1 ? T1 : which == 2 ? T2 : which == 3 ? T3 : T4;
  int id = (blockIdx.x & 255) * 256 + threadIdx.x;   // 65536 ids per weight
  int kk = id >> 8, n = id & 255;
  T[n * 256 + kk] = (__bf16)W[id];
}

// ---------- LayerNorm fp32-in -> bf16-out, one wave per token ----------
__global__ __launch_bounds__(256) void ln_fp32_kernel(const float* __restrict__ in,
    const float* __restrict__ g, const float* __restrict__ bb,
    __bf16* __restrict__ out) {
  int wid = (blockIdx.x * 256 + threadIdx.x) >> 6;
  int lane = threadIdx.x & 63;
  const float4 v = *(const float4*)(in + (size_t)wid * 256 + lane * 4);
  float s = v.x + v.y + v.z + v.w;
  #pragma unroll
  for (int off = 32; off; off >>= 1) s += __shfl_down(s, off);
  float mean = __shfl(s, 0) * (1.0f / 256.0f);
  float dx = v.x - mean, dy = v.y - mean, dz = v.z - mean, dw = v.w - mean;
  float vs = dx * dx + dy * dy + dz * dz + dw * dw;
  #pragma unroll
  for (int off = 32; off; off >>= 1) vs += __shfl_down(vs, off);
  float rstd = rsqrtf(__shfl(vs, 0) * (1.0f / 256.0f) + 1e-5f);
  const float4 gg = *(const float4*)(g + lane * 4);
  const float4 bv = *(const float4*)(bb + lane * 4);
  bf16x4 o4;
  o4[0] = (__bf16)(dx * rstd * gg.x + bv.x);
  o4[1] = (__bf16)(dy * rstd * gg.y + bv.y);
  o4[2] = (__bf16)(dz * rstd * gg.z + bv.z);
  o4[3] = (__bf16)(dw * rstd * gg.w + bv.w);
  *(bf16x4*)(out + (size_t)wid * 256 + lane * 4) = o4;
}

// ---------- LayerNorm bf16-in -> bf16-out ----------
__global__ __launch_bounds__(256) void ln_bf16_kernel(const __bf16* __restrict__ in,
    const float* __restrict__ g, const float* __restrict__ bb,
    __bf16* __restrict__ out) {
  int wid = (blockIdx.x * 256 + threadIdx.x) >> 6;
  int lane = threadIdx.x & 63;
  bf16x4 iv = *(const bf16x4*)(in + (size_t)wid * 256 + lane * 4);
  float vx = (float)iv[0], vy = (float)iv[1], vz = (float)iv[2], vw = (float)iv[3];
  float s = vx + vy + vz + vw;
  #pragma unroll
  for (int off = 32; off; off >>= 1) s += __shfl_down(s, off);
  float mean = __shfl(s, 0) * (1.0f / 256.0f);
  float dx = vx - mean, dy = vy - mean, dz = vz - mean, dw = vw - mean;
  float vs = dx * dx + dy * dy + dz * dz + dw * dw;
  #pragma unroll
  for (int off = 32; off; off >>= 1) vs += __shfl_down(vs, off);
  float rstd = rsqrtf(__shfl(vs, 0) * (1.0f / 256.0f) + 1e-5f);
  const float4 gg = *(const float4*)(g + lane * 4);
  const float4 bv = *(const float4*)(bb + lane * 4);
  bf16x4 o4;
  o4[0] = (__bf16)(dx * rstd * gg.x + bv.x);
  o4[1] = (__bf16)(dy * rstd * gg.y + bv.y);
  o4[2] = (__bf16)(dz * rstd * gg.z + bv.z);
  o4[3] = (__bf16)(dw * rstd * gg.w + bv.w);
  *(bf16x4*)(out + (size_t)wid * 256 + lane * 4) = o4;
}

// ---------- 2x2 mean pool fp32 -> bf16 ----------
__global__ __launch_bounds__(256) void pool_kernel(const float* __restrict__ x,
    __bf16* __restrict__ xp) {
  int idx = blockIdx.x * 256 + threadIdx.x;   // 4096*64
  int t = idx >> 6, c4 = (idx & 63) << 2;
  int b = t >> 10, rem = t & 1023;
  int i = rem >> 5, j = rem & 31;
  size_t base = ((size_t)b * 4096 + i * 128 + j * 2) * 256 + c4;
  float4 a0 = *(const float4*)(x + base);
  float4 a1 = *(const float4*)(x + base + 256);
  float4 a2 = *(const float4*)(x + base + 16384);
  float4 a3 = *(const float4*)(x + base + 16640);
  bf16x4 o4;
  o4[0] = (__bf16)(0.25f * (a0.x + a1.x + a2.x + a3.x));
  o4[1] = (__bf16)(0.25f * (a0.y + a1.y + a2.y + a3.y));
  o4[2] = (__bf16)(0.25f * (a0.z + a1.z + a2.z + a3.z));
  o4[3] = (__bf16)(0.25f * (a0.w + a1.w + a2.w + a3.w));
  *(bf16x4*)(xp + (size_t)t * 256 + c4) = o4;
}

// ---------- MFMA GEMM: C[M,256] = A[M,256] @ W (Wt[n][k] bf16) + bias ----------
// mode 0: C bf16 natural [M][256]
// mode 1: C bf16 transposed-per-batch vT[(b*256+n)*1024 + tloc]  (M = 4096)
// mode 2: C fp32 [M][256] + resid
__global__ __launch_bounds__(256) void gemm_mfma(
    const __bf16* __restrict__ A, const __bf16* __restrict__ Wt,
    const float* __restrict__ bias, const float* __restrict__ resid,
    void* __restrict__ Cout, int mode) {
  const int tid = threadIdx.x;
  const int w = tid >> 6, l = tid & 63;
  const int col = l & 15, quad = l >> 4;
  const int row0 = blockIdx.x * 64 + w * 16;
  const int col0 = blockIdx.y * 64;
  f32x4 acc[4] = {{0.f,0.f,0.f,0.f},{0.f,0.f,0.f,0.f},{0.f,0.f,0.f,0.f},{0.f,0.f,0.f,0.f}};
  const __bf16* ap = A + (size_t)(row0 + col) * 256 + quad * 8;
  #pragma unroll
  for (int ks = 0; ks < 8; ++ks) {
    bf16x8 af = *(const bf16x8*)(ap + ks * 32);
    #pragma unroll
    for (int n = 0; n < 4; ++n) {
      bf16x8 bf = *(const bf16x8*)(Wt + (size_t)(col0 + n * 16 + col) * 256 + ks * 32 + quad * 8);
      acc[n] = __builtin_amdgcn_mfma_f32_16x16x32_bf16(af, bf, acc[n], 0, 0, 0);
    }
  }
  const int rbase = row0 + quad * 4;
  #pragma unroll
  for (int n = 0; n < 4; ++n) {
    const int cc = col0 + n * 16 + col;
    const float bv = bias ? bias[cc] : 0.0f;
    if (mode == 0) {
      __bf16* C = (__bf16*)Cout;
      #pragma unroll
      for (int r = 0; r < 4; ++r)
        C[(size_t)(rbase + r) * 256 + cc] = (__bf16)(acc[n][r] + bv);
    } else if (mode == 1) {
      __bf16* C = (__bf16*)Cout;
      const int bb2 = rbase >> 10, tl = rbase & 1023;
      bf16x4 o4;
      #pragma unroll
      for (int r = 0; r < 4; ++r) o4[r] = (__bf16)(acc[n][r] + bv);
      *(bf16x4*)(C + ((size_t)(bb2 * 256 + cc)) * 1024 + tl) = o4;
    } else {
      float* C = (float*)Cout;
      #pragma unroll
      for (int r = 0; r < 4; ++r) {
        size_t off = (size_t)(rbase + r) * 256 + cc;
        C[off] = acc[n][r] + bv + resid[off];
      }
    }
  }
}

// ---------- fused attention: QK^T -> softmax -> PV -> (deferred attn write) ----------
// block = (q-tile of 16 rows, bh); 256 threads = 4 waves.
// LDS score tile Ss[16][1024] fp32, swizzle c ^ ((row&7)<<2):
//   phase-1 scalar writes: 2-way (free); phase-2 b128 row reads: conflict-free;
//   phase-3 b128 A-frag reads (row=lane&15, c=k0+quad*8): 8 lanes x 8 bank-groups
//   uniform = conflict-free (old (row&3)<<3 swizzle used only even groups -> 2x slow).
__device__ __forceinline__ int swz(int row, int c) {
  return row * 1024 + (c ^ ((row & 7) << 2));
}

__global__ __launch_bounds__(256) void attn_fused(
    const __bf16* __restrict__ q, const __bf16* __restrict__ kb,
    const __bf16* __restrict__ vT, float* __restrict__ attn,
    __bf16* __restrict__ oat) {
  __shared__ float Ss[16 * 1024];     // 64 KiB: scores then UNNORMALIZED exp
  __shared__ float part[64 * 32];     //  8 KiB: cross-wave PV reduce (separate -> Ss survives)
  __shared__ float inv_s[16];         // per-row 1/sum
  const int tid = threadIdx.x;
  const int w = tid >> 6, l = tid & 63;
  const int col = l & 15, quad = l >> 4;
  const int bh = blockIdx.y, b = bh >> 3, h = bh & 7;
  const int q0 = blockIdx.x * 16;

  // Phase 1: S = SCALE * Q K^T for this wave's 256-col strip
  bf16x8 qf = *(const bf16x8*)(q + ((size_t)(b * 4096 + q0 + col)) * 256 + h * 32 + quad * 8);
  const __bf16* kbase = kb + ((size_t)(b * 1024 + col)) * 256 + h * 32 + quad * 8;
  #pragma unroll 4
  for (int t = 0; t < 16; ++t) {
    int j0 = w * 256 + t * 16;
    bf16x8 kf = *(const bf16x8*)(kbase + (size_t)j0 * 256);
    f32x4 c = {0.f, 0.f, 0.f, 0.f};
    c = __builtin_amdgcn_mfma_f32_16x16x32_bf16(qf, kf, c, 0, 0, 0);
    #pragma unroll
    for (int r = 0; r < 4; ++r)
      Ss[swz(quad * 4 + r, j0 + col)] = c[r] * SCALE;
  }
  __syncthreads();

  // Phase 2: softmax stats for rows w*4..w*4+3; write back UNNORMALIZED exp.
  // No global stores here -> no vmcnt(0) drain at the next barrier.
  #pragma unroll
  for (int rr = 0; rr < 4; ++rr) {
    int row = w * 4 + rr;
    float4 v4[4];
    float m = -1e30f;
    #pragma unroll
    for (int i = 0; i < 4; ++i) {
      v4[i] = *(const float4*)(&Ss[swz(row, i * 256 + l * 4)]);
      m = fmaxf(m, fmaxf(fmaxf(v4[i].x, v4[i].y), fmaxf(v4[i].z, v4[i].w)));
    }
    #pragma unroll
    for (int off = 32; off; off >>= 1) m = fmaxf(m, __shfl_down(m, off));
    m = __shfl(m, 0);
    float s = 0.f;
    #pragma unroll
    for (int i = 0; i < 4; ++i) {
      v4[i].x = __expf(v4[i].x - m); v4[i].y = __expf(v4[i].y - m);
      v4[i].z = __expf(v4[i].z - m); v4[i].w = __expf(v4[i].w - m);
      s += v4[i].x + v4[i].y + v4[i].z + v4[i].w;
    }
    #pragma unroll
    for (int off = 32; off; off >>= 1) s += __shfl_down(s, off);
    if (l == 0) inv_s[row] = 1.0f / __shfl(s, 0);
    #pragma unroll
    for (int i = 0; i < 4; ++i)
      *(float4*)(&Ss[swz(row, i * 256 + l * 4)]) = v4[i];
  }
  __syncthreads();

  // Phase 3: partial PV over this wave's 256-col strip (two 16-wide d tiles).
  // Probs unnormalized; 1/sum folded into the reduce epilogue.
  f32x4 a0 = {0.f, 0.f, 0.f, 0.f}, a1 = {0.f, 0.f, 0.f, 0.f};
  const __bf16* v0p = vT + ((size_t)(b * 256 + h * 32 + col)) * 1024;
  const __bf16* v1p = v0p + 16 * 1024;
  #pragma unroll 2
  for (int s8 = 0; s8 < 8; ++s8) {
    int k0 = w * 256 + s8 * 32;
    int c0 = k0 + quad * 8;
    // p1 must be re-swizzled (base+4 is not XOR-consistent with (row&7)<<2)
    f32x4 p0 = *(const f32x4*)(&Ss[swz(col, c0)]);
    f32x4 p1 = *(const f32x4*)(&Ss[swz(col, c0 + 4)]);
    bf16x8 af;
    af[0] = (__bf16)p0[0]; af[1] = (__bf16)p0[1]; af[2] = (__bf16)p0[2]; af[3] = (__bf16)p0[3];
    af[4] = (__bf16)p1[0]; af[5] = (__bf16)p1[1]; af[6] = (__bf16)p1[2]; af[7] = (__bf16)p1[3];
    bf16x8 b0 = *(const bf16x8*)(v0p + k0 + quad * 8);
    bf16x8 b1 = *(const bf16x8*)(v1p + k0 + quad * 8);
    a0 = __builtin_amdgcn_mfma_f32_16x16x32_bf16(af, b0, a0, 0, 0, 0);
    a1 = __builtin_amdgcn_mfma_f32_16x16x32_bf16(af, b1, a1, 0, 0, 0);
  }

  // cross-wave reduce via separate part buffer (no barrier needed before writes)
  #pragma unroll
  for (int r = 0; r < 4; ++r) {
    part[(w * 16 + quad * 4 + r) * 32 + col] = a0[r];
    part[(w * 16 + quad * 4 + r) * 32 + 16 + col] = a1[r];
  }
  __syncthreads();
  int idx = tid;
  #pragma unroll
  for (int it = 0; it < 2; ++it, idx += 256) {
    int row = idx >> 5, d = idx & 31;
    float sum = (part[row * 32 + d] + part[(16 + row) * 32 + d]
               + part[(32 + row) * 32 + d] + part[(48 + row) * 32 + d]) * inv_s[row];
    oat[((size_t)(b * 4096 + q0 + row)) * 256 + h * 32 + d] = (__bf16)sum;
  }

  // Final: stream normalized attn (nontemporal -> bypass L2; write-once data).
  // All barriers done; drain overlaps next blocks' compute.
  float* abase = attn + ((size_t)bh * 4096 + q0) * 1024;
  int c4 = tid * 4;
  #pragma unroll 4
  for (int row = 0; row < 16; ++row) {
    f32x4 pv = *(const f32x4*)(&Ss[swz(row, c4)]);
    float iv = inv_s[row];
    pv[0] *= iv; pv[1] *= iv; pv[2] *= iv; pv[3] *= iv;
    __builtin_nontemporal_store(pv, (f32x4*)(abase + (size_t)row * 1024 + c4));
  }
}

extern "C" void kernel_launch(void* const* d_in, const int* in_sizes, int n_in,
                              void* d_out, int out_size, void* d_ws, size_t ws_size,
                              hipStream_t stream) {
  (void)in_sizes; (void)n_in; (void)out_size; (void)ws_size;
  const float* x     = (const float*)d_in[0];
  const float* ln1_g = (const float*)d_in[2];
  const float* ln1_b = (const float*)d_in[3];
  const float* Wq    = (const float*)d_in[4];
  const float* bq    = (const float*)d_in[5];
  const float* Wk    = (const float*)d_in[6];
  const float* bk    = (const float*)d_in[7];
  const float* Wv    = (const float*)d_in[8];
  const float* bv    = (const float*)d_in[9];
  const float* Wmean = (const float*)d_in[10];
  const float* ln2_g = (const float*)d_in[11];
  const float* ln2_b = (const float*)d_in[12];
  const float* Wo    = (const float*)d_in[13];
  const float* bo    = (const float*)d_in[14];

  float* out  = (float*)d_out;           // [16384, 256] fp32
  float* attn = out + 4194304;           // [32, 4096, 1024] fp32

  __bf16* w0   = (__bf16*)d_ws;
  __bf16* xn   = w0;                     // 4,194,304
  __bf16* qb   = w0 + 4194304;           // 4,194,304
  __bf16* oat  = w0 + 8388608;           // 4,194,304
  __bf16* xp   = w0 + 12582912;          // 1,048,576
  __bf16* xrm  = w0 + 13631488;          // 1,048,576
  __bf16* xr   = w0 + 14680064;          // 1,048,576
  __bf16* kbuf = w0 + 15728640;          // 1,048,576
  __bf16* vTb  = w0 + 16777216;          // 1,048,576
  __bf16* WtQ  = w0 + 17825792;          // 5 x 65,536
  __bf16* WtK  = WtQ + 65536;
  __bf16* WtV  = WtK + 65536;
  __bf16* WtM  = WtV + 65536;
  __bf16* WtO  = WtM + 65536;

  castw_kernel<<<1280, 256, 0, stream>>>(Wq, Wk, Wv, Wmean, Wo, WtQ, WtK, WtV, WtM, WtO);

  ln_fp32_kernel<<<4096, 256, 0, stream>>>(x, ln1_g, ln1_b, xn);
  gemm_mfma<<<dim3(256, 4), 256, 0, stream>>>(xn, WtQ, bq, nullptr, qb, 0);
  pool_kernel<<<1024, 256, 0, stream>>>(x, xp);
  gemm_mfma<<<dim3(64, 4), 256, 0, stream>>>(xp, WtM, nullptr, nullptr, xrm, 0);
  ln_bf16_kernel<<<1024, 256, 0, stream>>>(xrm, ln2_g, ln2_b, xr);
  gemm_mfma<<<dim3(64, 4), 256, 0, stream>>>(xr, WtK, bk, nullptr, kbuf, 0);
  gemm_mfma<<<dim3(64, 4), 256, 0, stream>>>(xr, WtV, bv, nullptr, vTb, 1);
  attn_fused<<<dim3(256, 32), 256, 0, stream>>>(qb, kbuf, vTb, attn, oat);
  gemm_mfma<<<dim3(256, 4), 256, 0, stream>>>(oat, WtO, bo, x, (void*)out, 2);
}